// Round 1
// baseline (3058.477 us; speedup 1.0000x reference)
//
#include <hip/hip_runtime.h>
#include <cfloat>

// Problem constants (fixed by the reference: N=65536, D=256, K=4096)
constexpr int N  = 65536;
constexpr int D  = 256;
constexpr int K  = 4096;
constexpr int BM = 128;   // rows (points) per workgroup
constexpr int BN = 128;   // centers per tile
constexpr int KD = 16;    // depth chunk staged in LDS

// ---------------- c2[k] = sum_d C[k][d]^2 ----------------
__global__ void prep_c2(const float* __restrict__ C, float* __restrict__ c2) {
    int k = blockIdx.x;
    int l = threadIdx.x;                 // 64 threads = 1 wave per center row
    const float4* row = (const float4*)(C + (size_t)k * D);
    float4 v = row[l];
    float s = v.x*v.x + v.y*v.y + v.z*v.z + v.w*v.w;
    #pragma unroll
    for (int m = 1; m < 64; m <<= 1) s += __shfl_xor(s, m);
    if (l == 0) c2[k] = s;
}

// ---------------- main: fused GEMM + argmin + scatter + loss ----------------
__global__ __launch_bounds__(256, 2) void assign_kernel(
        const float* __restrict__ X, const float* __restrict__ C,
        const float* __restrict__ c2, float* __restrict__ out_labels,
        float* __restrict__ seg, int* __restrict__ cnt,
        double* __restrict__ lossAcc)
{
    __shared__ float As[KD][BM];   // depth-major: As[kk][row]
    __shared__ float Bs[KD][BN];   // depth-major: Bs[kk][col]
    __shared__ float x2s[BM];
    __shared__ int   labs[BM];

    const int t  = threadIdx.x;
    const int tx = t & 15;         // center-group owner (16)
    const int ty = t >> 4;         // row-group owner (16)
    const int rowbase = blockIdx.x * BM;

    // --- x2 for this row block (2 threads per row) ---
    {
        int r  = t >> 1;
        int dh = (t & 1) * (D / 2);
        const float4* xr = (const float4*)(X + (size_t)(rowbase + r) * D + dh);
        float s = 0.f;
        #pragma unroll
        for (int i = 0; i < D / 8; ++i) {
            float4 v = xr[i];
            s += v.x*v.x + v.y*v.y + v.z*v.z + v.w*v.w;
        }
        s += __shfl_xor(s, 1);
        if ((t & 1) == 0) x2s[r] = s;
    }
    __syncthreads();

    // per-thread rows: {4ty..4ty+3} and {64+4ty..64+4ty+3}
    float x2v[8];
    #pragma unroll
    for (int i = 0; i < 4; ++i) {
        x2v[i]     = x2s[4*ty + i];
        x2v[i + 4] = x2s[64 + 4*ty + i];
    }

    float rmv[8];
    int   rmi[8];
    #pragma unroll
    for (int i = 0; i < 8; ++i) { rmv[i] = FLT_MAX; rmi[i] = 0x7fffffff; }

    for (int ct = 0; ct < K / BN; ++ct) {
        float acc[8][8];
        #pragma unroll
        for (int i = 0; i < 8; ++i)
            #pragma unroll
            for (int j = 0; j < 8; ++j) acc[i][j] = 0.f;

        // per-thread cols: {4tx..4tx+3} and {64+4tx..64+4tx+3}
        float c2f[8];
        {
            float4 a = *(const float4*)(c2 + ct*BN + 4*tx);
            float4 b = *(const float4*)(c2 + ct*BN + 64 + 4*tx);
            c2f[0]=a.x; c2f[1]=a.y; c2f[2]=a.z; c2f[3]=a.w;
            c2f[4]=b.x; c2f[5]=b.y; c2f[6]=b.z; c2f[7]=b.w;
        }

        for (int dk = 0; dk < D / KD; ++dk) {
            // stage A and B tiles (KD x 128), coalesced global float4 reads,
            // depth-major LDS writes (2-lanes-per-bank pattern on rows)
            #pragma unroll
            for (int i = 0; i < 2; ++i) {
                int f  = t + 256 * i;     // float4 id 0..511
                int r  = f >> 2;          // 0..127
                int dp = f & 3;           // which float4 of the 16 depths
                float4 av = *(const float4*)(X + (size_t)(rowbase + r) * D + dk*KD + 4*dp);
                float4 bv = *(const float4*)(C + (size_t)(ct*BN + r) * D + dk*KD + 4*dp);
                As[4*dp + 0][r] = av.x; As[4*dp + 1][r] = av.y;
                As[4*dp + 2][r] = av.z; As[4*dp + 3][r] = av.w;
                Bs[4*dp + 0][r] = bv.x; Bs[4*dp + 1][r] = bv.y;
                Bs[4*dp + 2][r] = bv.z; Bs[4*dp + 3][r] = bv.w;
            }
            __syncthreads();
            #pragma unroll
            for (int kk = 0; kk < KD; ++kk) {
                float4 a0 = *(const float4*)&As[kk][4*ty];
                float4 a1 = *(const float4*)&As[kk][64 + 4*ty];
                float4 b0 = *(const float4*)&Bs[kk][4*tx];
                float4 b1 = *(const float4*)&Bs[kk][64 + 4*tx];
                float av[8] = {a0.x,a0.y,a0.z,a0.w,a1.x,a1.y,a1.z,a1.w};
                float bv[8] = {b0.x,b0.y,b0.z,b0.w,b1.x,b1.y,b1.z,b1.w};
                #pragma unroll
                for (int i = 0; i < 8; ++i)
                    #pragma unroll
                    for (int j = 0; j < 8; ++j)
                        acc[i][j] = fmaf(av[i], bv[j], acc[i][j]);
            }
            __syncthreads();
        }

        // epilogue: d2 = (x2 - 2*dot) + c2, fused argmin (first-min tie-break)
        #pragma unroll
        for (int i = 0; i < 8; ++i) {
            float bv = FLT_MAX; int bi = 0x7fffffff;
            #pragma unroll
            for (int j = 0; j < 8; ++j) {
                int coll = (j < 4) ? (4*tx + j) : (64 + 4*tx + (j - 4));
                float v = fmaf(-2.f, acc[i][j], x2v[i]) + c2f[j];
                int idx = ct * BN + coll;
                if (v < bv || (v == bv && idx < bi)) { bv = v; bi = idx; }
            }
            #pragma unroll
            for (int m = 1; m < 16; m <<= 1) {    // butterfly over tx lanes
                float ov = __shfl_xor(bv, m);
                int   oi = __shfl_xor(bi, m);
                if (ov < bv || (ov == bv && oi < bi)) { bv = ov; bi = oi; }
            }
            if (bv < rmv[i] || (bv == rmv[i] && bi < rmi[i])) { rmv[i] = bv; rmi[i] = bi; }
        }
    }

    // write labels (as FLOAT: d_out is one flat f32 buffer) + counts
    if (tx == 0) {
        #pragma unroll
        for (int i = 0; i < 8; ++i) {
            int r = (i < 4) ? (4*ty + i) : (64 + 4*ty + (i - 4));
            labs[r] = rmi[i];
            out_labels[rowbase + r] = (float)rmi[i];
            atomicAdd(&cnt[rmi[i]], 1);
        }
    }
    __syncthreads();

    // scatter: seg_sum[label] += x ; loss += (x - c_label)^2
    {
        int r   = t >> 1;
        int dh  = (t & 1) * (D / 2);
        int lab = labs[r];
        const float4* xr = (const float4*)(X + (size_t)(rowbase + r) * D + dh);
        const float4* cr = (const float4*)(C + (size_t)lab * D + dh);
        float* sp = seg + (size_t)lab * D + dh;
        float ls = 0.f;
        #pragma unroll 8
        for (int i = 0; i < D / 8; ++i) {
            float4 xv = xr[i];
            float4 cv = cr[i];
            atomicAdd(sp + 4*i + 0, xv.x);
            atomicAdd(sp + 4*i + 1, xv.y);
            atomicAdd(sp + 4*i + 2, xv.z);
            atomicAdd(sp + 4*i + 3, xv.w);
            float d0 = xv.x - cv.x, d1 = xv.y - cv.y;
            float d2 = xv.z - cv.z, d3 = xv.w - cv.w;
            ls += d0*d0 + d1*d1 + d2*d2 + d3*d3;
        }
        #pragma unroll
        for (int m = 1; m < 64; m <<= 1) ls += __shfl_xor(ls, m);
        if ((t & 63) == 0) atomicAdd(lossAcc, (double)ls);
    }
}

// ---------------- finalize: new_centers, new_counts, loss ----------------
__global__ void finalize_kernel(const float* __restrict__ C,
                                const int* __restrict__ counts0,
                                const float* __restrict__ seg,
                                const int* __restrict__ cnt,
                                const double* __restrict__ lossAcc,
                                float* __restrict__ out)
{
    int g = blockIdx.x * 256 + threadIdx.x;   // 0 .. K*D-1
    int k = g >> 8;                           // D = 256
    float c0 = (float)counts0[k];
    float m  = (float)cnt[k];
    out[N + g] = (c0 * C[g] + seg[g]) / (c0 + m);
    if (g < K) out[N + (size_t)K*D + g] = (float)(counts0[g] + cnt[g]);
    if (g == 0) out[N + (size_t)K*D + K] = (float)(lossAcc[0] / (double)N);
}

extern "C" void kernel_launch(void* const* d_in, const int* in_sizes, int n_in,
                              void* d_out, int out_size, void* d_ws, size_t ws_size,
                              hipStream_t stream) {
    const float* X       = (const float*)d_in[0];   // [N, D]
    const float* C       = (const float*)d_in[1];   // [K, D]
    const int*   counts0 = (const int*)d_in[2];     // [K]
    float* out = (float*)d_out;

    // workspace layout
    float*  seg     = (float*)d_ws;                       // K*D floats
    int*    cnt     = (int*)(seg + (size_t)K * D);        // K ints
    float*  c2      = (float*)(cnt + K);                  // K floats
    double* lossAcc = (double*)(c2 + K);                  // 1 double (8B aligned)

    size_t zero_bytes = ((size_t)K * D + 2 * (size_t)K) * 4 + 16;
    hipMemsetAsync(d_ws, 0, zero_bytes, stream);

    prep_c2<<<K, 64, 0, stream>>>(C, c2);
    assign_kernel<<<N / BM, 256, 0, stream>>>(X, C, c2, out, seg, cnt, lossAcc);
    finalize_kernel<<<(K * D) / 256, 256, 0, stream>>>(C, counts0, seg, cnt, lossAcc, out);
}

// Round 2
// 1568.812 us; speedup vs baseline: 1.9496x; 1.9496x over previous
//
#include <hip/hip_runtime.h>
#include <cfloat>
#include <cstdint>

// Problem constants (fixed by the reference: N=65536, D=256, K=4096)
constexpr int N  = 65536;
constexpr int D  = 256;
constexpr int K  = 4096;

typedef __attribute__((ext_vector_type(8))) short short8;            // bf16x8 MFMA frag
typedef __attribute__((ext_vector_type(8))) unsigned short ushort8;  // 16B vector
typedef __attribute__((ext_vector_type(4))) float floatx4;

__device__ inline floatx4 mfma_bf16(short8 a, short8 b, floatx4 c) {
    return __builtin_amdgcn_mfma_f32_16x16x32_bf16(a, b, c, 0, 0, 0);
}

// ---------------- c2[k] = sum_d C[k][d]^2 (exact fp32) ----------------
__global__ void prep_c2(const float* __restrict__ C, float* __restrict__ c2) {
    int k = blockIdx.x;
    int l = threadIdx.x;                 // 64 threads = 1 wave per center row
    const float4* row = (const float4*)(C + (size_t)k * D);
    float4 v = row[l];
    float s = v.x*v.x + v.y*v.y + v.z*v.z + v.w*v.w;
    #pragma unroll
    for (int m = 1; m < 64; m <<= 1) s += __shfl_xor(s, m);
    if (l == 0) c2[k] = s;
}

// ---------------- fp32 -> bf16 hi/lo split (truncation; lo exact residual) -----
__global__ void convert_split(const float* __restrict__ src,
                              unsigned short* __restrict__ hi,
                              unsigned short* __restrict__ lo, int n8) {
    int id = blockIdx.x * 256 + threadIdx.x;
    if (id >= n8) return;
    const float4* s4 = (const float4*)src;
    float4 a = s4[2*id], b = s4[2*id+1];
    float xs[8] = {a.x,a.y,a.z,a.w,b.x,b.y,b.z,b.w};
    ushort8 h, l8;
    #pragma unroll
    for (int i = 0; i < 8; ++i) {
        unsigned int bits = __float_as_uint(xs[i]);
        float hf = __uint_as_float(bits & 0xFFFF0000u);
        float lof = xs[i] - hf;                       // exact (same-exponent prefix)
        h[i]  = (unsigned short)(bits >> 16);
        l8[i] = (unsigned short)(__float_as_uint(lof) >> 16);
    }
    ((ushort8*)hi)[id] = h;
    ((ushort8*)lo)[id] = l8;
}

// ---------------- split-bf16 MFMA GEMM + fused top-2 argmin ----------------
// 256 thr = 4 waves (2x2), tile 128x128, BK=32, wave tile 64x64 = 4x4 frags 16x16x32.
// Score = c2[col] - 2*dot  (x2 omitted: constant per row, argmin-invariant).
// Output: cand[row][half] = (v1, idx1, v2, idx2) per 2048-col half.
__global__ __launch_bounds__(256, 2) void mfma_assign(
        const unsigned short* __restrict__ Xhi, const unsigned short* __restrict__ Xlo,
        const unsigned short* __restrict__ Chi, const unsigned short* __restrict__ Clo,
        const float* __restrict__ c2, float* __restrict__ cand)
{
    // +8 ushort pad per row: frag b128 reads & staging writes are conflict-even
    __shared__ unsigned short sAh[128][40], sAl[128][40];
    __shared__ unsigned short sBh[128][40], sBl[128][40];

    const int t    = threadIdx.x;
    const int w    = t >> 6, l = t & 63;
    const int quad = l >> 4, lr = l & 15;
    const int wm   = w >> 1, wn = w & 1;
    const int rowbase = blockIdx.x * 128;

    // per-lane running top-2 per owned row (16 rows: st = 4*i + r)
    float v1[16], v2[16]; int x1[16], x2s[16];
    #pragma unroll
    for (int i = 0; i < 16; ++i) { v1[i]=FLT_MAX; v2[i]=FLT_MAX; x1[i]=0x7fffffff; x2s[i]=0x7fffffff; }

    const int rA = t >> 2, sA = t & 3;   // staging: 4 ushort8-chunks per 32-depth row

    for (int ct = 0; ct < K/128; ++ct) {
        floatx4 acc[4][4];
        #pragma unroll
        for (int i = 0; i < 4; ++i)
            #pragma unroll
            for (int j = 0; j < 4; ++j) acc[i][j] = (floatx4)0.f;

        float c2v[4]; int jidx[4];
        #pragma unroll
        for (int j = 0; j < 4; ++j) {
            int col = ct*128 + 64*wn + 16*j + lr;
            c2v[j] = c2[col]; jidx[j] = col;
        }

        for (int dk = 0; dk < D/32; ++dk) {
            __syncthreads();
            {
                size_t ax = (size_t)(rowbase + rA) * D + dk*32 + 8*sA;
                size_t bx = (size_t)(ct*128 + rA)  * D + dk*32 + 8*sA;
                *(ushort8*)&sAh[rA][8*sA]      = *(const ushort8*)&Xhi[ax];
                *(ushort8*)&sAh[rA + 64][8*sA] = *(const ushort8*)&Xhi[ax + (size_t)64*D];
                *(ushort8*)&sAl[rA][8*sA]      = *(const ushort8*)&Xlo[ax];
                *(ushort8*)&sAl[rA + 64][8*sA] = *(const ushort8*)&Xlo[ax + (size_t)64*D];
                *(ushort8*)&sBh[rA][8*sA]      = *(const ushort8*)&Chi[bx];
                *(ushort8*)&sBh[rA + 64][8*sA] = *(const ushort8*)&Chi[bx + (size_t)64*D];
                *(ushort8*)&sBl[rA][8*sA]      = *(const ushort8*)&Clo[bx];
                *(ushort8*)&sBl[rA + 64][8*sA] = *(const ushort8*)&Clo[bx + (size_t)64*D];
            }
            __syncthreads();

            short8 Ah[4], Al[4];
            #pragma unroll
            for (int i = 0; i < 4; ++i) {
                Ah[i] = (short8)*(const ushort8*)&sAh[64*wm + 16*i + lr][quad*8];
                Al[i] = (short8)*(const ushort8*)&sAl[64*wm + 16*i + lr][quad*8];
            }
            #pragma unroll
            for (int j = 0; j < 4; ++j) {
                short8 Bh = (short8)*(const ushort8*)&sBh[64*wn + 16*j + lr][quad*8];
                short8 Bl = (short8)*(const ushort8*)&sBl[64*wn + 16*j + lr][quad*8];
                #pragma unroll
                for (int i = 0; i < 4; ++i) {
                    acc[i][j] = mfma_bf16(Ah[i], Bh, acc[i][j]);
                    acc[i][j] = mfma_bf16(Ah[i], Bl, acc[i][j]);
                    acc[i][j] = mfma_bf16(Al[i], Bh, acc[i][j]);
                }
            }
        }

        // fused top-2 merge: per lane, rows st=4i+r (row=64wm+16i+4quad+r), cols jidx[j]
        #pragma unroll
        for (int i = 0; i < 4; ++i)
            #pragma unroll
            for (int j = 0; j < 4; ++j)
                #pragma unroll
                for (int r = 0; r < 4; ++r) {
                    float s = fmaf(-2.f, acc[i][j][r], c2v[j]);
                    int st = 4*i + r;
                    bool cA = s < v1[st];
                    bool cB = s < v2[st];
                    float tv = cB ? s : v2[st]; int tx = cB ? jidx[j] : x2s[st];
                    v2[st] = cA ? v1[st] : tv;  x2s[st] = cA ? x1[st] : tx;
                    v1[st] = cA ? s : v1[st];   x1[st]  = cA ? jidx[j] : x1[st];
                }
    }

    // final cross-lane (16 lr lanes) top-2 butterfly per owned row, then write
    #pragma unroll
    for (int i = 0; i < 4; ++i)
        #pragma unroll
        for (int r = 0; r < 4; ++r) {
            int st = 4*i + r;
            float a1 = v1[st], a2 = v2[st]; int ax1 = x1[st], ax2 = x2s[st];
            #pragma unroll
            for (int m = 1; m < 16; m <<= 1) {
                float b1 = __shfl_xor(a1, m); int bx1 = __shfl_xor(ax1, m);
                float b2 = __shfl_xor(a2, m); int bx2 = __shfl_xor(ax2, m);
                bool tt = (b1 < a1) || (b1 == a1 && bx1 < ax1);
                float n1 = tt ? b1 : a1; int nx1 = tt ? bx1 : ax1;
                float w1 = tt ? a1 : b1; int wx1 = tt ? ax1 : bx1;  // loser of firsts
                float w2 = tt ? b2 : a2; int wx2 = tt ? bx2 : ax2;  // winner's second
                bool uu = (w2 < w1) || (w2 == w1 && wx2 < wx1);
                a1 = n1; ax1 = nx1;
                a2 = uu ? w2 : w1; ax2 = uu ? wx2 : wx1;
            }
            if (lr == 0) {
                int row = rowbase + 64*wm + 16*i + 4*quad + r;
                float4 o; o.x = a1; o.y = __int_as_float(ax1);
                o.z = a2; o.w = __int_as_float(ax2);
                ((float4*)cand)[row*2 + wn] = o;
            }
        }
}

// ---------------- exact fp32 recheck of 4 candidates + scatter + loss --------
__global__ __launch_bounds__(256) void recheck_scatter(
        const float* __restrict__ X, const float* __restrict__ C,
        const float* __restrict__ c2, const float* __restrict__ cand,
        float* __restrict__ out_labels, float* __restrict__ seg,
        int* __restrict__ cnt, double* __restrict__ lossAcc)
{
    int t = threadIdx.x, w = t >> 6, l = t & 63;
    int row = blockIdx.x * 4 + w;                     // one wave per point
    const float4* c4 = (const float4*)cand;
    float4 p0 = c4[row*2], p1 = c4[row*2 + 1];
    int idx[4] = {__float_as_int(p0.y), __float_as_int(p0.w),
                  __float_as_int(p1.y), __float_as_int(p1.w)};

    float4 xv = ((const float4*)X)[(size_t)row*64 + l];
    float s[5];
    s[4] = xv.x*xv.x + xv.y*xv.y + xv.z*xv.z + xv.w*xv.w;
    #pragma unroll
    for (int k = 0; k < 4; ++k) {
        float4 cv = ((const float4*)C)[(size_t)idx[k]*64 + l];
        s[k] = xv.x*cv.x + xv.y*cv.y + xv.z*cv.z + xv.w*cv.w;
    }
    #pragma unroll
    for (int m = 1; m < 64; m <<= 1) {
        #pragma unroll
        for (int k = 0; k < 5; ++k) s[k] += __shfl_xor(s[k], m);
    }
    float x2 = s[4];
    float best = FLT_MAX; int bi = 0x7fffffff;
    #pragma unroll
    for (int k = 0; k < 4; ++k) {
        float d2 = fmaf(-2.f, s[k], x2) + c2[idx[k]];   // numpy's rounding order
        if (d2 < best || (d2 == best && idx[k] < bi)) { best = d2; bi = idx[k]; }
    }
    if (l == 0) { out_labels[row] = (float)bi; atomicAdd(&cnt[bi], 1); }

    float4 cb = ((const float4*)C)[(size_t)bi*64 + l];
    float* sp = seg + (size_t)bi*D + 4*l;
    atomicAdd(sp + 0, xv.x); atomicAdd(sp + 1, xv.y);
    atomicAdd(sp + 2, xv.z); atomicAdd(sp + 3, xv.w);
    float d0 = xv.x - cb.x, d1 = xv.y - cb.y, d2_ = xv.z - cb.z, d3 = xv.w - cb.w;
    float ls = d0*d0 + d1*d1 + d2_*d2_ + d3*d3;
    #pragma unroll
    for (int m = 1; m < 64; m <<= 1) ls += __shfl_xor(ls, m);
    if (l == 0) atomicAdd(lossAcc, (double)ls);
}

// ---------------- finalize: new_centers, new_counts, loss ----------------
__global__ void finalize_kernel(const float* __restrict__ C,
                                const int* __restrict__ counts0,
                                const float* __restrict__ seg,
                                const int* __restrict__ cnt,
                                const double* __restrict__ lossAcc,
                                float* __restrict__ out)
{
    int g = blockIdx.x * 256 + threadIdx.x;   // 0 .. K*D-1
    int k = g >> 8;                           // D = 256
    float c0 = (float)counts0[k];
    float m  = (float)cnt[k];
    out[N + g] = (c0 * C[g] + seg[g]) / (c0 + m);
    if (g < K) out[N + (size_t)K*D + g] = (float)(counts0[g] + cnt[g]);
    if (g == 0) out[N + (size_t)K*D + K] = (float)(lossAcc[0] / (double)N);
}

// ================= fallback (round-1 proven fp32 path, small ws) =============
__global__ __launch_bounds__(256, 2) void assign_fp32(
        const float* __restrict__ X, const float* __restrict__ C,
        const float* __restrict__ c2, float* __restrict__ out_labels,
        float* __restrict__ seg, int* __restrict__ cnt,
        double* __restrict__ lossAcc)
{
    constexpr int BM = 128, BN = 128, KD = 16;
    __shared__ float As[KD][BM];
    __shared__ float Bs[KD][BN];
    __shared__ float x2f[BM];
    __shared__ int   labs[BM];

    const int t  = threadIdx.x;
    const int tx = t & 15;
    const int ty = t >> 4;
    const int rowbase = blockIdx.x * BM;

    {
        int r  = t >> 1;
        int dh = (t & 1) * (D / 2);
        const float4* xr = (const float4*)(X + (size_t)(rowbase + r) * D + dh);
        float s = 0.f;
        #pragma unroll
        for (int i = 0; i < D / 8; ++i) {
            float4 v = xr[i];
            s += v.x*v.x + v.y*v.y + v.z*v.z + v.w*v.w;
        }
        s += __shfl_xor(s, 1);
        if ((t & 1) == 0) x2f[r] = s;
    }
    __syncthreads();

    float x2v[8];
    #pragma unroll
    for (int i = 0; i < 4; ++i) { x2v[i] = x2f[4*ty + i]; x2v[i+4] = x2f[64 + 4*ty + i]; }

    float rmv[8]; int rmi[8];
    #pragma unroll
    for (int i = 0; i < 8; ++i) { rmv[i] = FLT_MAX; rmi[i] = 0x7fffffff; }

    for (int ct = 0; ct < K / BN; ++ct) {
        float acc[8][8];
        #pragma unroll
        for (int i = 0; i < 8; ++i)
            #pragma unroll
            for (int j = 0; j < 8; ++j) acc[i][j] = 0.f;

        float c2f2[8];
        {
            float4 a = *(const float4*)(c2 + ct*BN + 4*tx);
            float4 b = *(const float4*)(c2 + ct*BN + 64 + 4*tx);
            c2f2[0]=a.x; c2f2[1]=a.y; c2f2[2]=a.z; c2f2[3]=a.w;
            c2f2[4]=b.x; c2f2[5]=b.y; c2f2[6]=b.z; c2f2[7]=b.w;
        }

        for (int dk = 0; dk < D / KD; ++dk) {
            #pragma unroll
            for (int i = 0; i < 2; ++i) {
                int f  = t + 256 * i;
                int r  = f >> 2;
                int dp = f & 3;
                float4 av = *(const float4*)(X + (size_t)(rowbase + r) * D + dk*KD + 4*dp);
                float4 bv = *(const float4*)(C + (size_t)(ct*BN + r) * D + dk*KD + 4*dp);
                As[4*dp+0][r]=av.x; As[4*dp+1][r]=av.y; As[4*dp+2][r]=av.z; As[4*dp+3][r]=av.w;
                Bs[4*dp+0][r]=bv.x; Bs[4*dp+1][r]=bv.y; Bs[4*dp+2][r]=bv.z; Bs[4*dp+3][r]=bv.w;
            }
            __syncthreads();
            #pragma unroll
            for (int kk = 0; kk < KD; ++kk) {
                float4 a0 = *(const float4*)&As[kk][4*ty];
                float4 a1 = *(const float4*)&As[kk][64 + 4*ty];
                float4 b0 = *(const float4*)&Bs[kk][4*tx];
                float4 b1 = *(const float4*)&Bs[kk][64 + 4*tx];
                float av[8] = {a0.x,a0.y,a0.z,a0.w,a1.x,a1.y,a1.z,a1.w};
                float bv[8] = {b0.x,b0.y,b0.z,b0.w,b1.x,b1.y,b1.z,b1.w};
                #pragma unroll
                for (int i = 0; i < 8; ++i)
                    #pragma unroll
                    for (int j = 0; j < 8; ++j)
                        acc[i][j] = fmaf(av[i], bv[j], acc[i][j]);
            }
            __syncthreads();
        }

        #pragma unroll
        for (int i = 0; i < 8; ++i) {
            float bv = FLT_MAX; int bi = 0x7fffffff;
            #pragma unroll
            for (int j = 0; j < 8; ++j) {
                int coll = (j < 4) ? (4*tx + j) : (64 + 4*tx + (j - 4));
                float v = fmaf(-2.f, acc[i][j], x2v[i]) + c2f2[j];
                int idx = ct * BN + coll;
                if (v < bv || (v == bv && idx < bi)) { bv = v; bi = idx; }
            }
            #pragma unroll
            for (int m = 1; m < 16; m <<= 1) {
                float ov = __shfl_xor(bv, m);
                int   oi = __shfl_xor(bi, m);
                if (ov < bv || (ov == bv && oi < bi)) { bv = ov; bi = oi; }
            }
            if (bv < rmv[i] || (bv == rmv[i] && bi < rmi[i])) { rmv[i] = bv; rmi[i] = bi; }
        }
    }

    if (tx == 0) {
        #pragma unroll
        for (int i = 0; i < 8; ++i) {
            int r = (i < 4) ? (4*ty + i) : (64 + 4*ty + (i - 4));
            labs[r] = rmi[i];
            out_labels[rowbase + r] = (float)rmi[i];
            atomicAdd(&cnt[rmi[i]], 1);
        }
    }
    __syncthreads();

    {
        int r   = t >> 1;
        int dh  = (t & 1) * (D / 2);
        int lab = labs[r];
        const float4* xr = (const float4*)(X + (size_t)(rowbase + r) * D + dh);
        const float4* cr = (const float4*)(C + (size_t)lab * D + dh);
        float* sp = seg + (size_t)lab * D + dh;
        float ls = 0.f;
        #pragma unroll 8
        for (int i = 0; i < D / 8; ++i) {
            float4 xv = xr[i];
            float4 cv = cr[i];
            atomicAdd(sp + 4*i + 0, xv.x);
            atomicAdd(sp + 4*i + 1, xv.y);
            atomicAdd(sp + 4*i + 2, xv.z);
            atomicAdd(sp + 4*i + 3, xv.w);
            float d0 = xv.x - cv.x, d1 = xv.y - cv.y;
            float d2 = xv.z - cv.z, d3 = xv.w - cv.w;
            ls += d0*d0 + d1*d1 + d2*d2 + d3*d3;
        }
        #pragma unroll
        for (int m = 1; m < 64; m <<= 1) ls += __shfl_xor(ls, m);
        if ((t & 63) == 0) atomicAdd(lossAcc, (double)ls);
    }
}

extern "C" void kernel_launch(void* const* d_in, const int* in_sizes, int n_in,
                              void* d_out, int out_size, void* d_ws, size_t ws_size,
                              hipStream_t stream) {
    const float* X       = (const float*)d_in[0];   // [N, D]
    const float* C       = (const float*)d_in[1];   // [K, D]
    const int*   counts0 = (const int*)d_in[2];     // [K]
    float* out = (float*)d_out;

    // workspace layout
    char* p = (char*)d_ws;
    float*  seg     = (float*)p;          p += (size_t)K * D * 4;   // 4 MB
    int*    cnt     = (int*)p;            p += (size_t)K * 4;       // 16 KB
    float*  c2      = (float*)p;          p += (size_t)K * 4;       // 16 KB
    double* lossAcc = (double*)p;         p += 16;
    size_t zero_bytes = (size_t)(p - (char*)d_ws);
    float*  cand    = (float*)p;          p += (size_t)N * 8 * 4;   // 2 MB
    unsigned short* Xhi = (unsigned short*)p; p += (size_t)N * D * 2;
    unsigned short* Xlo = (unsigned short*)p; p += (size_t)N * D * 2;
    unsigned short* Chi = (unsigned short*)p; p += (size_t)K * D * 2;
    unsigned short* Clo = (unsigned short*)p; p += (size_t)K * D * 2;
    size_t need = (size_t)(p - (char*)d_ws);                        // ~74 MB

    hipMemsetAsync(d_ws, 0, zero_bytes, stream);
    prep_c2<<<K, 64, 0, stream>>>(C, c2);

    if (ws_size >= need) {
        convert_split<<<(N*D/8 + 255)/256, 256, 0, stream>>>(X, Xhi, Xlo, N*D/8);
        convert_split<<<(K*D/8 + 255)/256, 256, 0, stream>>>(C, Chi, Clo, K*D/8);
        mfma_assign<<<N/128, 256, 0, stream>>>(Xhi, Xlo, Chi, Clo, c2, cand);
        recheck_scatter<<<N/4, 256, 0, stream>>>(X, C, c2, cand, out, seg, cnt, lossAcc);
    } else {
        assign_fp32<<<N/128, 256, 0, stream>>>(X, C, c2, out, seg, cnt, lossAcc);
    }
    finalize_kernel<<<(K*D)/256, 256, 0, stream>>>(C, counts0, seg, cnt, lossAcc, out);
}

// Round 3
// 1099.524 us; speedup vs baseline: 2.7816x; 1.4268x over previous
//
#include <hip/hip_runtime.h>
#include <cfloat>
#include <cstdint>

// Problem constants (fixed by the reference: N=65536, D=256, K=4096)
constexpr int N  = 65536;
constexpr int D  = 256;
constexpr int K  = 4096;

typedef __attribute__((ext_vector_type(8))) short short8;            // bf16x8 MFMA frag
typedef __attribute__((ext_vector_type(8))) unsigned short ushort8;  // 16B vector
typedef __attribute__((ext_vector_type(4))) float floatx4;

__device__ inline floatx4 mfma_bf16(short8 a, short8 b, floatx4 c) {
    return __builtin_amdgcn_mfma_f32_16x16x32_bf16(a, b, c, 0, 0, 0);
}

// ---------------- c2[k] = sum_d C[k][d]^2 (exact fp32) ----------------
__global__ void prep_c2(const float* __restrict__ C, float* __restrict__ c2) {
    int k = blockIdx.x;
    int l = threadIdx.x;                 // 64 threads = 1 wave per center row
    const float4* row = (const float4*)(C + (size_t)k * D);
    float4 v = row[l];
    float s = v.x*v.x + v.y*v.y + v.z*v.z + v.w*v.w;
    #pragma unroll
    for (int m = 1; m < 64; m <<= 1) s += __shfl_xor(s, m);
    if (l == 0) c2[k] = s;
}

// ---------------- fp32 -> bf16 hi/lo split (truncation; lo exact residual) -----
__global__ void convert_split(const float* __restrict__ src,
                              unsigned short* __restrict__ hi,
                              unsigned short* __restrict__ lo, int n8) {
    int id = blockIdx.x * 256 + threadIdx.x;
    if (id >= n8) return;
    const float4* s4 = (const float4*)src;
    float4 a = s4[2*id], b = s4[2*id+1];
    float xs[8] = {a.x,a.y,a.z,a.w,b.x,b.y,b.z,b.w};
    ushort8 h, l8;
    #pragma unroll
    for (int i = 0; i < 8; ++i) {
        unsigned int bits = __float_as_uint(xs[i]);
        float hf = __uint_as_float(bits & 0xFFFF0000u);
        float lof = xs[i] - hf;                       // exact (same-exponent prefix)
        h[i]  = (unsigned short)(bits >> 16);
        l8[i] = (unsigned short)(__float_as_uint(lof) >> 16);
    }
    ((ushort8*)hi)[id] = h;
    ((ushort8*)lo)[id] = l8;
}

// ---------------- split-bf16 MFMA GEMM + fused top-2 argmin ----------------
// 256 thr = 4 waves (2x2), tile 128x128, BK=32, wave tile 64x64 = 4x4 frags 16x16x32.
// Score = c2[col] - 2*dot  (x2 omitted: constant per row, argmin-invariant).
// Output: cand[row][half] = (v1, idx1, v2, idx2) per 2048-col half.
__global__ __launch_bounds__(256, 2) void mfma_assign(
        const unsigned short* __restrict__ Xhi, const unsigned short* __restrict__ Xlo,
        const unsigned short* __restrict__ Chi, const unsigned short* __restrict__ Clo,
        const float* __restrict__ c2, float* __restrict__ cand)
{
    // +8 ushort pad per row: frag b128 reads & staging writes are conflict-even
    __shared__ unsigned short sAh[128][40], sAl[128][40];
    __shared__ unsigned short sBh[128][40], sBl[128][40];

    const int t    = threadIdx.x;
    const int w    = t >> 6, l = t & 63;
    const int quad = l >> 4, lr = l & 15;
    const int wm   = w >> 1, wn = w & 1;
    const int rowbase = blockIdx.x * 128;

    // per-lane running top-2 per owned row (16 rows: st = 4*i + r)
    float v1[16], v2[16]; int x1[16], x2s[16];
    #pragma unroll
    for (int i = 0; i < 16; ++i) { v1[i]=FLT_MAX; v2[i]=FLT_MAX; x1[i]=0x7fffffff; x2s[i]=0x7fffffff; }

    const int rA = t >> 2, sA = t & 3;   // staging: 4 ushort8-chunks per 32-depth row

    for (int ct = 0; ct < K/128; ++ct) {
        floatx4 acc[4][4];
        #pragma unroll
        for (int i = 0; i < 4; ++i)
            #pragma unroll
            for (int j = 0; j < 4; ++j) acc[i][j] = (floatx4)0.f;

        float c2v[4]; int jidx[4];
        #pragma unroll
        for (int j = 0; j < 4; ++j) {
            int col = ct*128 + 64*wn + 16*j + lr;
            c2v[j] = c2[col]; jidx[j] = col;
        }

        for (int dk = 0; dk < D/32; ++dk) {
            __syncthreads();
            {
                size_t ax = (size_t)(rowbase + rA) * D + dk*32 + 8*sA;
                size_t bx = (size_t)(ct*128 + rA)  * D + dk*32 + 8*sA;
                *(ushort8*)&sAh[rA][8*sA]      = *(const ushort8*)&Xhi[ax];
                *(ushort8*)&sAh[rA + 64][8*sA] = *(const ushort8*)&Xhi[ax + (size_t)64*D];
                *(ushort8*)&sAl[rA][8*sA]      = *(const ushort8*)&Xlo[ax];
                *(ushort8*)&sAl[rA + 64][8*sA] = *(const ushort8*)&Xlo[ax + (size_t)64*D];
                *(ushort8*)&sBh[rA][8*sA]      = *(const ushort8*)&Chi[bx];
                *(ushort8*)&sBh[rA + 64][8*sA] = *(const ushort8*)&Chi[bx + (size_t)64*D];
                *(ushort8*)&sBl[rA][8*sA]      = *(const ushort8*)&Clo[bx];
                *(ushort8*)&sBl[rA + 64][8*sA] = *(const ushort8*)&Clo[bx + (size_t)64*D];
            }
            __syncthreads();

            short8 Ah[4], Al[4];
            #pragma unroll
            for (int i = 0; i < 4; ++i) {
                Ah[i] = (short8)*(const ushort8*)&sAh[64*wm + 16*i + lr][quad*8];
                Al[i] = (short8)*(const ushort8*)&sAl[64*wm + 16*i + lr][quad*8];
            }
            #pragma unroll
            for (int j = 0; j < 4; ++j) {
                short8 Bh = (short8)*(const ushort8*)&sBh[64*wn + 16*j + lr][quad*8];
                short8 Bl = (short8)*(const ushort8*)&sBl[64*wn + 16*j + lr][quad*8];
                #pragma unroll
                for (int i = 0; i < 4; ++i) {
                    acc[i][j] = mfma_bf16(Ah[i], Bh, acc[i][j]);
                    acc[i][j] = mfma_bf16(Ah[i], Bl, acc[i][j]);
                    acc[i][j] = mfma_bf16(Al[i], Bh, acc[i][j]);
                }
            }
        }

        // fused top-2 merge: per lane, rows st=4i+r (row=64wm+16i+4quad+r), cols jidx[j]
        #pragma unroll
        for (int i = 0; i < 4; ++i)
            #pragma unroll
            for (int j = 0; j < 4; ++j)
                #pragma unroll
                for (int r = 0; r < 4; ++r) {
                    float s = fmaf(-2.f, acc[i][j][r], c2v[j]);
                    int st = 4*i + r;
                    bool cA = s < v1[st];
                    bool cB = s < v2[st];
                    float tv = cB ? s : v2[st]; int tx = cB ? jidx[j] : x2s[st];
                    v2[st] = cA ? v1[st] : tv;  x2s[st] = cA ? x1[st] : tx;
                    v1[st] = cA ? s : v1[st];   x1[st]  = cA ? jidx[j] : x1[st];
                }
    }

    // final cross-lane (16 lr lanes) top-2 butterfly per owned row, then write
    #pragma unroll
    for (int i = 0; i < 4; ++i)
        #pragma unroll
        for (int r = 0; r < 4; ++r) {
            int st = 4*i + r;
            float a1 = v1[st], a2 = v2[st]; int ax1 = x1[st], ax2 = x2s[st];
            #pragma unroll
            for (int m = 1; m < 16; m <<= 1) {
                float b1 = __shfl_xor(a1, m); int bx1 = __shfl_xor(ax1, m);
                float b2 = __shfl_xor(a2, m); int bx2 = __shfl_xor(ax2, m);
                bool tt = (b1 < a1) || (b1 == a1 && bx1 < ax1);
                float n1 = tt ? b1 : a1; int nx1 = tt ? bx1 : ax1;
                float w1 = tt ? a1 : b1; int wx1 = tt ? ax1 : bx1;  // loser of firsts
                float w2 = tt ? b2 : a2; int wx2 = tt ? bx2 : ax2;  // winner's second
                bool uu = (w2 < w1) || (w2 == w1 && wx2 < wx1);
                a1 = n1; ax1 = nx1;
                a2 = uu ? w2 : w1; ax2 = uu ? wx2 : wx1;
            }
            if (lr == 0) {
                int row = rowbase + 64*wm + 16*i + 4*quad + r;
                float4 o; o.x = a1; o.y = __int_as_float(ax1);
                o.z = a2; o.w = __int_as_float(ax2);
                ((float4*)cand)[row*2 + wn] = o;
            }
        }
}

// ------- exact fp32 recheck of 4 candidates + labels + histogram + loss ------
__global__ __launch_bounds__(256) void recheck_label(
        const float* __restrict__ X, const float* __restrict__ C,
        const float* __restrict__ c2, const float* __restrict__ cand,
        float* __restrict__ out_labels, int* __restrict__ labInt,
        int* __restrict__ cnt, double* __restrict__ lossAcc)
{
    __shared__ double lpart[4];
    int t = threadIdx.x, w = t >> 6, l = t & 63;
    int row = blockIdx.x * 4 + w;                     // one wave per point
    const float4* c4 = (const float4*)cand;
    float4 p0 = c4[row*2], p1 = c4[row*2 + 1];
    int idx[4] = {__float_as_int(p0.y), __float_as_int(p0.w),
                  __float_as_int(p1.y), __float_as_int(p1.w)};

    float4 xv = ((const float4*)X)[(size_t)row*64 + l];
    float s[5];
    s[4] = xv.x*xv.x + xv.y*xv.y + xv.z*xv.z + xv.w*xv.w;
    #pragma unroll
    for (int k = 0; k < 4; ++k) {
        float4 cv = ((const float4*)C)[(size_t)idx[k]*64 + l];
        s[k] = xv.x*cv.x + xv.y*cv.y + xv.z*cv.z + xv.w*cv.w;
    }
    #pragma unroll
    for (int m = 1; m < 64; m <<= 1) {
        #pragma unroll
        for (int k = 0; k < 5; ++k) s[k] += __shfl_xor(s[k], m);
    }
    float x2 = s[4];
    float best = FLT_MAX; int bi = 0x7fffffff;
    #pragma unroll
    for (int k = 0; k < 4; ++k) {
        float d2 = fmaf(-2.f, s[k], x2) + c2[idx[k]];   // numpy's rounding order
        if (d2 < best || (d2 == best && idx[k] < bi)) { best = d2; bi = idx[k]; }
    }
    if (l == 0) {
        out_labels[row] = (float)bi;
        labInt[row] = bi;
        atomicAdd(&cnt[bi], 1);
        lpart[w] = (double)best;
    }
    __syncthreads();
    if (t == 0)
        atomicAdd(lossAcc, lpart[0] + lpart[1] + lpart[2] + lpart[3]);
}

// ---------------- exclusive prefix sum of the 4096-bin histogram -------------
__global__ void prefix_kernel(const int* __restrict__ cnt,
                              int* __restrict__ offs, int* __restrict__ cursor) {
    int l = threadIdx.x;                 // 64 lanes, 64 bins each
    int s = 0;
    #pragma unroll 8
    for (int i = 0; i < 64; ++i) s += cnt[l*64 + i];
    int inc = s;
    #pragma unroll
    for (int off = 1; off < 64; off <<= 1) {
        int u = __shfl_up(inc, off);
        if (l >= off) inc += u;
    }
    int run = inc - s;                   // exclusive lane base
    for (int i = 0; i < 64; ++i) {
        int k = l*64 + i;
        offs[k] = run; cursor[k] = run;
        run += cnt[k];
    }
}

// ---------------- bucket rows by label (one position atomic per row) ---------
__global__ void scatter_idx(const int* __restrict__ labInt,
                            int* __restrict__ cursor, int* __restrict__ sortedIdx) {
    int i = blockIdx.x * 256 + threadIdx.x;
    int lab = labInt[i];
    int pos = atomicAdd(&cursor[lab], 1);
    sortedIdx[pos] = i;
}

// -------- atomic-free segment sum (block per center) + fused finalize --------
__global__ __launch_bounds__(256) void center_update(
        const float* __restrict__ X, const float* __restrict__ C,
        const int* __restrict__ counts0, const int* __restrict__ cnt,
        const int* __restrict__ offs, const int* __restrict__ sortedIdx,
        const double* __restrict__ lossAcc, float* __restrict__ out)
{
    int k = blockIdx.x, d = threadIdx.x;   // d = dim (D == 256 == blockDim)
    int start = offs[k], m = cnt[k];
    float acc = 0.f;
    int i = 0;
    for (; i + 4 <= m; i += 4) {
        int r0 = sortedIdx[start+i],   r1 = sortedIdx[start+i+1];
        int r2 = sortedIdx[start+i+2], r3 = sortedIdx[start+i+3];
        float a0 = X[(size_t)r0*D + d], a1 = X[(size_t)r1*D + d];
        float a2 = X[(size_t)r2*D + d], a3 = X[(size_t)r3*D + d];
        acc += (a0 + a1) + (a2 + a3);
    }
    for (; i < m; ++i) acc += X[(size_t)sortedIdx[start+i]*D + d];

    float c0 = (float)counts0[k];
    out[N + (size_t)k*D + d] = (c0 * C[(size_t)k*D + d] + acc) / (c0 + (float)m);
    if (d == 0) out[N + (size_t)K*D + k] = (float)(counts0[k] + m);
    if (k == 0 && d == 0) out[N + (size_t)K*D + K] = (float)(lossAcc[0] / (double)N);
}

// ---------------- finalize (fallback path only) ----------------
__global__ void finalize_kernel(const float* __restrict__ C,
                                const int* __restrict__ counts0,
                                const float* __restrict__ seg,
                                const int* __restrict__ cnt,
                                const double* __restrict__ lossAcc,
                                float* __restrict__ out)
{
    int g = blockIdx.x * 256 + threadIdx.x;   // 0 .. K*D-1
    int k = g >> 8;                           // D = 256
    float c0 = (float)counts0[k];
    float m  = (float)cnt[k];
    out[N + g] = (c0 * C[g] + seg[g]) / (c0 + m);
    if (g < K) out[N + (size_t)K*D + g] = (float)(counts0[g] + cnt[g]);
    if (g == 0) out[N + (size_t)K*D + K] = (float)(lossAcc[0] / (double)N);
}

// ================= fallback (round-1 proven fp32 path, small ws) =============
__global__ __launch_bounds__(256, 2) void assign_fp32(
        const float* __restrict__ X, const float* __restrict__ C,
        const float* __restrict__ c2, float* __restrict__ out_labels,
        float* __restrict__ seg, int* __restrict__ cnt,
        double* __restrict__ lossAcc)
{
    constexpr int BM = 128, BN = 128, KD = 16;
    __shared__ float As[KD][BM];
    __shared__ float Bs[KD][BN];
    __shared__ float x2f[BM];
    __shared__ int   labs[BM];

    const int t  = threadIdx.x;
    const int tx = t & 15;
    const int ty = t >> 4;
    const int rowbase = blockIdx.x * BM;

    {
        int r  = t >> 1;
        int dh = (t & 1) * (D / 2);
        const float4* xr = (const float4*)(X + (size_t)(rowbase + r) * D + dh);
        float s = 0.f;
        #pragma unroll
        for (int i = 0; i < D / 8; ++i) {
            float4 v = xr[i];
            s += v.x*v.x + v.y*v.y + v.z*v.z + v.w*v.w;
        }
        s += __shfl_xor(s, 1);
        if ((t & 1) == 0) x2f[r] = s;
    }
    __syncthreads();

    float x2v[8];
    #pragma unroll
    for (int i = 0; i < 4; ++i) { x2v[i] = x2f[4*ty + i]; x2v[i+4] = x2f[64 + 4*ty + i]; }

    float rmv[8]; int rmi[8];
    #pragma unroll
    for (int i = 0; i < 8; ++i) { rmv[i] = FLT_MAX; rmi[i] = 0x7fffffff; }

    for (int ct = 0; ct < K / BN; ++ct) {
        float acc[8][8];
        #pragma unroll
        for (int i = 0; i < 8; ++i)
            #pragma unroll
            for (int j = 0; j < 8; ++j) acc[i][j] = 0.f;

        float c2f2[8];
        {
            float4 a = *(const float4*)(c2 + ct*BN + 4*tx);
            float4 b = *(const float4*)(c2 + ct*BN + 64 + 4*tx);
            c2f2[0]=a.x; c2f2[1]=a.y; c2f2[2]=a.z; c2f2[3]=a.w;
            c2f2[4]=b.x; c2f2[5]=b.y; c2f2[6]=b.z; c2f2[7]=b.w;
        }

        for (int dk = 0; dk < D / KD; ++dk) {
            #pragma unroll
            for (int i = 0; i < 2; ++i) {
                int f  = t + 256 * i;
                int r  = f >> 2;
                int dp = f & 3;
                float4 av = *(const float4*)(X + (size_t)(rowbase + r) * D + dk*KD + 4*dp);
                float4 bv = *(const float4*)(C + (size_t)(ct*BN + r) * D + dk*KD + 4*dp);
                As[4*dp+0][r]=av.x; As[4*dp+1][r]=av.y; As[4*dp+2][r]=av.z; As[4*dp+3][r]=av.w;
                Bs[4*dp+0][r]=bv.x; Bs[4*dp+1][r]=bv.y; Bs[4*dp+2][r]=bv.z; Bs[4*dp+3][r]=bv.w;
            }
            __syncthreads();
            #pragma unroll
            for (int kk = 0; kk < KD; ++kk) {
                float4 a0 = *(const float4*)&As[kk][4*ty];
                float4 a1 = *(const float4*)&As[kk][64 + 4*ty];
                float4 b0 = *(const float4*)&Bs[kk][4*tx];
                float4 b1 = *(const float4*)&Bs[kk][64 + 4*tx];
                float av[8] = {a0.x,a0.y,a0.z,a0.w,a1.x,a1.y,a1.z,a1.w};
                float bv[8] = {b0.x,b0.y,b0.z,b0.w,b1.x,b1.y,b1.z,b1.w};
                #pragma unroll
                for (int i = 0; i < 8; ++i)
                    #pragma unroll
                    for (int j = 0; j < 8; ++j)
                        acc[i][j] = fmaf(av[i], bv[j], acc[i][j]);
            }
            __syncthreads();
        }

        #pragma unroll
        for (int i = 0; i < 8; ++i) {
            float bv = FLT_MAX; int bi = 0x7fffffff;
            #pragma unroll
            for (int j = 0; j < 8; ++j) {
                int coll = (j < 4) ? (4*tx + j) : (64 + 4*tx + (j - 4));
                float v = fmaf(-2.f, acc[i][j], x2v[i]) + c2f2[j];
                int idx = ct * BN + coll;
                if (v < bv || (v == bv && idx < bi)) { bv = v; bi = idx; }
            }
            #pragma unroll
            for (int m = 1; m < 16; m <<= 1) {
                float ov = __shfl_xor(bv, m);
                int   oi = __shfl_xor(bi, m);
                if (ov < bv || (ov == bv && oi < bi)) { bv = ov; bi = oi; }
            }
            if (bv < rmv[i] || (bv == rmv[i] && bi < rmi[i])) { rmv[i] = bv; rmi[i] = bi; }
        }
    }

    if (tx == 0) {
        #pragma unroll
        for (int i = 0; i < 8; ++i) {
            int r = (i < 4) ? (4*ty + i) : (64 + 4*ty + (i - 4));
            labs[r] = rmi[i];
            out_labels[rowbase + r] = (float)rmi[i];
            atomicAdd(&cnt[rmi[i]], 1);
        }
    }
    __syncthreads();

    {
        int r   = t >> 1;
        int dh  = (t & 1) * (D / 2);
        int lab = labs[r];
        const float4* xr = (const float4*)(X + (size_t)(rowbase + r) * D + dh);
        const float4* cr = (const float4*)(C + (size_t)lab * D + dh);
        float* sp = seg + (size_t)lab * D + dh;
        float ls = 0.f;
        #pragma unroll 8
        for (int i = 0; i < D / 8; ++i) {
            float4 xv = xr[i];
            float4 cv = cr[i];
            atomicAdd(sp + 4*i + 0, xv.x);
            atomicAdd(sp + 4*i + 1, xv.y);
            atomicAdd(sp + 4*i + 2, xv.z);
            atomicAdd(sp + 4*i + 3, xv.w);
            float d0 = xv.x - cv.x, d1 = xv.y - cv.y;
            float d2 = xv.z - cv.z, d3 = xv.w - cv.w;
            ls += d0*d0 + d1*d1 + d2*d2 + d3*d3;
        }
        #pragma unroll
        for (int m = 1; m < 64; m <<= 1) ls += __shfl_xor(ls, m);
        if ((t & 63) == 0) atomicAdd(lossAcc, (double)ls);
    }
}

extern "C" void kernel_launch(void* const* d_in, const int* in_sizes, int n_in,
                              void* d_out, int out_size, void* d_ws, size_t ws_size,
                              hipStream_t stream) {
    const float* X       = (const float*)d_in[0];   // [N, D]
    const float* C       = (const float*)d_in[1];   // [K, D]
    const int*   counts0 = (const int*)d_in[2];     // [K]
    float* out = (float*)d_out;

    // workspace layout
    char* p = (char*)d_ws;
    float*  seg     = (float*)p;          p += (size_t)K * D * 4;   // 4 MB (fallback)
    int*    cnt     = (int*)p;            p += (size_t)K * 4;       // 16 KB
    float*  c2      = (float*)p;          p += (size_t)K * 4;       // 16 KB
    double* lossAcc = (double*)p;         p += 16;
    size_t zero_bytes = (size_t)(p - (char*)d_ws);
    float*  cand    = (float*)p;          p += (size_t)N * 8 * 4;   // 2 MB
    unsigned short* Xhi = (unsigned short*)p; p += (size_t)N * D * 2;
    unsigned short* Xlo = (unsigned short*)p; p += (size_t)N * D * 2;
    unsigned short* Chi = (unsigned short*)p; p += (size_t)K * D * 2;
    unsigned short* Clo = (unsigned short*)p; p += (size_t)K * D * 2;
    size_t need = (size_t)(p - (char*)d_ws);                        // ~74 MB

    // sort scratch reuses the seg region (mfma path never touches seg)
    int* labInt    = (int*)seg;                  // N ints   (256 KB)
    int* sortedIdx = labInt + N;                 // N ints   (256 KB)
    int* offs      = sortedIdx + N;              // K ints   (16 KB)
    int* cursor    = offs + K;                   // K ints   (16 KB)

    hipMemsetAsync(cnt, 0, (size_t)K * 4 + 4096, stream);  // cnt + c2 + lossAcc region
    prep_c2<<<K, 64, 0, stream>>>(C, c2);

    if (ws_size >= need) {
        convert_split<<<(N*D/8 + 255)/256, 256, 0, stream>>>(X, Xhi, Xlo, N*D/8);
        convert_split<<<(K*D/8 + 255)/256, 256, 0, stream>>>(C, Chi, Clo, K*D/8);
        mfma_assign<<<N/128, 256, 0, stream>>>(Xhi, Xlo, Chi, Clo, c2, cand);
        recheck_label<<<N/4, 256, 0, stream>>>(X, C, c2, cand, out, labInt, cnt, lossAcc);
        prefix_kernel<<<1, 64, 0, stream>>>(cnt, offs, cursor);
        scatter_idx<<<N/256, 256, 0, stream>>>(labInt, cursor, sortedIdx);
        center_update<<<K, 256, 0, stream>>>(X, C, counts0, cnt, offs, sortedIdx, lossAcc, out);
    } else {
        hipMemsetAsync(d_ws, 0, zero_bytes, stream);
        prep_c2<<<K, 64, 0, stream>>>(C, c2);
        assign_fp32<<<N/128, 256, 0, stream>>>(X, C, c2, out, seg, cnt, lossAcc);
        finalize_kernel<<<(K*D)/256, 256, 0, stream>>>(C, counts0, seg, cnt, lossAcc, out);
    }
}